// Round 21
// baseline (223.726 us; speedup 1.0000x reference)
//
#include <hip/hip_runtime.h>
#include <hip/hip_bf16.h>
#include <math.h>

// BinaryTreeLSTM — round 21: timeline optimization.
//  (a) prep split: prep_a packs xb/Wih_p/bge only (~67MB);
//  (b) Whh packing (100MB BW) folded into the gemm_gx dispatch as 8192
//      trailing blocks — hides ~16us under the compute-bound GEMM
//      (GX runs at 1.5 of 6.3 TB/s: big BW headroom);
//  (c) tail reverted to r16 exact form (KSX/act_tail was measured null).
// gemm_gx GEMM part and fused_level are the r16-proven best.
//
// Packed gate-interleaved column space: e = (j/16)*64 + g*16 + (j%16)
//   (orig W row g*2048+j). Wih_p[4096][1024], Whh_p[4096][2048] bf16,
//   XCD-affine 128-row tiles.
// GX[4096][4096] fp16: rows 0..2046 = bf16(emb[node]) @ Wih_p^T + bge;
//   rows >= 2047 (level-11) consumed in-register by the gemm_gx epilogue.
// Hcat: level-k h-slab at row OFF(k)=4096-2^(k+1), 2^k rows x 2048 bf16.
// c compact: level k writes even-node c at row m>>1 (1024 f32); k-1 reads row m.

#define TREE_DEPTH 12

typedef unsigned short u16;
typedef unsigned int u32;
typedef __attribute__((ext_vector_type(8))) short bf16x8;
typedef __attribute__((ext_vector_type(4))) float f32x4;
typedef __attribute__((ext_vector_type(8))) unsigned short u16x8;
typedef __attribute__((ext_vector_type(2))) unsigned int u32x2;

__device__ __forceinline__ void gload16(const void* g, void* l) {
    __builtin_amdgcn_global_load_lds(
        (const __attribute__((address_space(1))) u32*)g,
        (__attribute__((address_space(3))) u32*)l, 16, 0, 0);
}

__device__ __forceinline__ u16 f2bf(float f) {
    __hip_bfloat16 h = __float2bfloat16(f);
    return *reinterpret_cast<u16*>(&h);
}
__device__ __forceinline__ u16 f2h(float f) {
    _Float16 h = (_Float16)f;
    return *reinterpret_cast<u16*>(&h);
}
__device__ __forceinline__ float h2f(u16 u) {
    _Float16 h;
    *reinterpret_cast<u16*>(&h) = u;
    return (float)h;
}
__device__ __forceinline__ float fsig(float x) {
    return 1.0f / (1.0f + __expf(-x));
}
__device__ __forceinline__ float ftanh(float x) {
    return 1.0f - 2.0f / (1.0f + __expf(2.0f * x));
}

// ---------------------------------------------------------------- prep_a
// Blocks [0,4096): pack W_ih -> Wih_p; [4096,8191): emb -> xb bf16;
// [8191,8207): fuse bias into packed-e order.
__global__ void prep_a(const float* __restrict__ Wih,
                       const float* __restrict__ emb,
                       const float* __restrict__ b_ih,
                       const float* __restrict__ b_hh,
                       u16* __restrict__ Wih_p,
                       u16* __restrict__ xb, float* __restrict__ bge) {
    const int bid = blockIdx.x;
    if (bid < 4096) {
        const int b = bid;
        const int x = b & 7, t = b >> 3;   // t in [0,512)
        const int e = ((t & 3) * 8 + x) * 128 + (t >> 2);  // (e>>7)%8 == x
        const int g = (e >> 4) & 3;
        const int j = (e >> 6) * 16 + (e & 15);
        const int wr = g * 2048 + j;
        const int col = threadIdx.x * 4;
        f32x4 v = __builtin_nontemporal_load(
            (const f32x4*)(Wih + (size_t)wr * 1024 + col));
        u32x2 p;
        p[0] = (u32)f2bf(v[0]) | ((u32)f2bf(v[1]) << 16);
        p[1] = (u32)f2bf(v[2]) | ((u32)f2bf(v[3]) << 16);
        *reinterpret_cast<u32x2*>(Wih_p + (size_t)e * 1024 + col) = p;
    } else if (bid < 8191) {
        size_t idx = ((size_t)(bid - 4096) * 256 + threadIdx.x) * 4;
        f32x4 v = __builtin_nontemporal_load((const f32x4*)(emb + idx));
        u32x2 p;
        p[0] = (u32)f2bf(v[0]) | ((u32)f2bf(v[1]) << 16);
        p[1] = (u32)f2bf(v[2]) | ((u32)f2bf(v[3]) << 16);
        *reinterpret_cast<u32x2*>(xb + idx) = p;
    } else {
        int e = (bid - 8191) * 256 + threadIdx.x;   // 0..4095 packed order
        int g = (e >> 4) & 3;
        int j = (e >> 6) * 16 + (e & 15);
        int r = g * 2048 + j;
        bge[e] = b_ih[r] + b_hh[r];
    }
}

// ---------------------------------------------------------------- GX + packW
// Blocks [0,1024): r16-proven GEMM (128x128 tile, 4 waves, BK=64 swizzled).
//   Rows < 2047: GX fp16 (LDS-staged coalesced store). Rows >= 2047: L11 cell.
// Blocks [1024,9216): pack W_hh -> Whh_p (overlaps with the GEMM).
__global__ __launch_bounds__(256) void gx_pack(
    const u16* __restrict__ xb, const u16* __restrict__ Wp,
    const float* __restrict__ bge, u16* __restrict__ GX,
    u16* __restrict__ hdst, float* __restrict__ cdst,
    const float* __restrict__ Whh_f, u16* __restrict__ Whh_p)
{
    __shared__ u16 smem[128 * 140];   // staging uses [0, 256*64) u16

    const int bid = blockIdx.x;
    if (bid >= 1024) {
        // ---- Whh packer block
        const int b2 = bid - 1024;          // 0..8191
        const int seg = b2 >> 12;           // 0/1: low/high K half
        const int b = b2 & 4095;
        const int x = b & 7, t = b >> 3;
        const int e = ((t & 3) * 8 + x) * 128 + (t >> 2);
        const int g = (e >> 4) & 3;
        const int j = (e >> 6) * 16 + (e & 15);
        const int wr = g * 2048 + j;
        const int col = threadIdx.x * 4;
        f32x4 v = __builtin_nontemporal_load(
            (const f32x4*)(Whh_f + (size_t)wr * 2048 + seg * 1024 + col));
        u32x2 p;
        p[0] = (u32)f2bf(v[0]) | ((u32)f2bf(v[1]) << 16);
        p[1] = (u32)f2bf(v[2]) | ((u32)f2bf(v[3]) << 16);
        *reinterpret_cast<u32x2*>(Whh_p + (size_t)e * 2048 + seg * 1024 + col) = p;
        return;
    }

    // ---- GEMM block (r16-proven)
    const int x = bid & 7, t = bid >> 3;
    const int ct = (t & 3) * 8 + x;
    const int mt = t >> 2;
    const int m0 = mt * 128, c0 = ct * 128;

    const int tid = threadIdx.x, lane = tid & 63, w = tid >> 6;
    const int wr = (w >> 1) * 64, wc = (w & 1) * 64;

    f32x4 acc[4][4];
    #pragma unroll
    for (int i = 0; i < 4; ++i)
        #pragma unroll
        for (int j = 0; j < 4; ++j)
            acc[i][j] = f32x4{0.f, 0.f, 0.f, 0.f};

    const u16* gp[8];
    u16* dl[8];
    #pragma unroll
    for (int i = 0; i < 8; ++i) {
        const int s = tid + i * 256;
        const int r = s >> 3;
        const int o = (s & 7) * 16;
        const int ke = (o ^ ((r & 7) << 4)) >> 1;   // element offset 0..63
        gp[i] = (r < 128) ? xb + (size_t)(m0 + r) * 1024 + ke
                          : Wp + (size_t)(c0 + r - 128) * 1024 + ke;
        dl[i] = smem + s * 8;
    }

    const int fl = lane & 15;
    const int kunit = (lane >> 4) * 16;   // byte offset of fragment in k-chunk

    for (int k0 = 0; k0 < 1024; k0 += 64) {
        #pragma unroll
        for (int i = 0; i < 8; ++i) { gload16(gp[i], dl[i]); gp[i] += 64; }
        __syncthreads();
        #pragma unroll
        for (int ks = 0; ks < 2; ++ks) {
            bf16x8 a_[4], b_[4];
            #pragma unroll
            for (int i = 0; i < 4; ++i) {
                const int ar = wr + i * 16 + fl;
                const int byo = (ks * 64 + kunit) ^ ((ar & 7) << 4);
                a_[i] = *reinterpret_cast<const bf16x8*>(
                    reinterpret_cast<const char*>(smem + ar * 64) + byo);
            }
            #pragma unroll
            for (int j = 0; j < 4; ++j) {
                const int br = 128 + wc + j * 16 + fl;
                const int byo = (ks * 64 + kunit) ^ ((br & 7) << 4);
                b_[j] = *reinterpret_cast<const bf16x8*>(
                    reinterpret_cast<const char*>(smem + br * 64) + byo);
            }
            #pragma unroll
            for (int i = 0; i < 4; ++i)
                #pragma unroll
                for (int j = 0; j < 4; ++j)
                    acc[i][j] = __builtin_amdgcn_mfma_f32_16x16x32_bf16(
                        a_[i], b_[j], acc[i][j], 0, 0, 0);
        }
        __syncthreads();
    }

    const int rg = (lane >> 4) * 4;
    if (m0 < 2047) {
        #pragma unroll
        for (int i = 0; i < 4; ++i)
            #pragma unroll
            for (int j = 0; j < 4; ++j) {
                const float bv = bge[c0 + wc + j * 16 + fl];
                #pragma unroll
                for (int r = 0; r < 4; ++r)
                    smem[(wr + i * 16 + rg + r) * 140 + (wc + j * 16 + fl)] =
                        f2h(acc[i][j][r] + bv);
            }
        __syncthreads();
        const int row_ = tid >> 4, chunk = tid & 15;
        #pragma unroll
        for (int it = 0; it < 8; ++it) {
            const int row = it * 16 + row_;
            if (m0 + row < 2047) {
                u16x8 v = *reinterpret_cast<const u16x8*>(
                    &smem[row * 140 + chunk * 8]);
                __builtin_nontemporal_store(
                    v, (u16x8*)(GX + (size_t)(m0 + row) * 4096 + c0 + chunk * 8));
            }
        }
    }
    if (m0 + 127 >= 2047) {
        const int jj = ((c0 + wc) >> 6) * 16 + fl;
        const float bi  = bge[c0 + wc + fl];
        const float bgg = bge[c0 + wc + 32 + fl];
        const float bo  = bge[c0 + wc + 48 + fl];
        #pragma unroll
        for (int i = 0; i < 4; ++i) {
            #pragma unroll
            for (int r = 0; r < 4; ++r) {
                const int m = m0 + wr + i * 16 + rg + r;
                if (m < 2047 || m >= 4095) continue;
                const int mm = m - 2047;
                const float cn = fsig(acc[i][0][r] + bi) * ftanh(acc[i][2][r] + bgg);
                const float hn = fsig(acc[i][3][r] + bo) * ftanh(cn);
                hdst[(size_t)(mm >> 1) * 2048 + (mm & 1) * 1024 + jj] = f2bf(hn);
                if (!(mm & 1))
                    cdst[(size_t)(mm >> 1) * 1024 + jj] = cn;
            }
        }
    }
}

// ---------------------------------------------------------------- fused level
// gates = A(h_cat) @ Whh_p^T + GX[node]; K=2048 split KG ways in-block.
// BK=64, both-sides-swizzled LDS (r16-proven).
template <int MI, int MW, int NW, int KG>
__global__ __launch_bounds__(MW* NW* KG * 64) void fused_level(
    const u16* __restrict__ A, const u16* __restrict__ Wp,
    const u16* __restrict__ GXl, const float* __restrict__ cprev,
    u16* __restrict__ hnext, float* __restrict__ cnext,
    float* __restrict__ outp, int n)
{
    constexpr int BM = MI * 16 * MW;
    constexpr int BN = NW * 64;
    constexpr int S = MW * NW;
    constexpr int NFR = MI * 4;
    constexpr int RC = NFR > 8 ? 8 : NFR;
    constexpr int NP = NFR / RC;
    constexpr int ROWS = BM + BN;
    constexpr int SLOTS = ROWS * 8;       // 16B slots per BK=64 step
    constexpr int GT = S * 64;
    constexpr int NL = SLOTS / GT;
    static_assert(SLOTS % GT == 0, "slot mapping must be exact");
    constexpr int STG = KG * ROWS * 128;
    constexpr int REDB = (KG > 1) ? (KG - 1) * S * RC * 64 * 16 : 0;
    constexpr int SMEM = STG > REDB ? STG : REDB;
    __shared__ __align__(16) char smem[SMEM];

    const int gx_ = gridDim.x;
    int b = blockIdx.x + gx_ * blockIdx.y;
    const int x = b & 7;
    int t = b >> 3;
    int ct, mt;
    if constexpr (NW == 2) {
        ct = (t & 3) * 8 + x; mt = t >> 2;
    } else {
        const int lo = t & 1; t >>= 1;
        ct = ((t & 3) * 8 + x) * 2 + lo; mt = t >> 2;
    }
    const int m0 = mt * BM;
    const int c0 = ct * BN;

    const int tid = threadIdx.x;
    const int lane = tid & 63;
    const int w = tid >> 6;
    const int kg = w / S;
    const int slot = w % S;
    const int wm = slot / NW;
    const int wn = slot % NW;

    const int Kc = 2048 / KG;
    const int kbeg = kg * Kc;

    u16* buf = (u16*)smem + (size_t)kg * ROWS * 64;

    const int gtid = slot * 64 + lane;
    const u16* gp[NL];
    u16* dl[NL];
    #pragma unroll
    for (int i = 0; i < NL; ++i) {
        const int s = gtid + i * GT;
        const int r = s >> 3;
        const int o = (s & 7) * 16;
        const int ke = (o ^ ((r & 7) << 4)) >> 1;   // element 0..63
        if (r < BM) {
            int ar = m0 + r;
            if (ar >= n) ar = n - 1;
            gp[i] = A + (size_t)ar * 2048 + kbeg + ke;
        } else {
            gp[i] = Wp + (size_t)(c0 + r - BM) * 2048 + kbeg + ke;
        }
        dl[i] = buf + s * 8;
    }

    f32x4 acc[MI][4];
    #pragma unroll
    for (int mi = 0; mi < MI; ++mi)
        #pragma unroll
        for (int f = 0; f < 4; ++f)
            acc[mi][f] = f32x4{0.f, 0.f, 0.f, 0.f};

    const int fl = lane & 15;
    const int kunit = (lane >> 4) * 16;
    const int ar0 = wm * MI * 16;
    const int bc0 = BM;

    for (int k0 = 0; k0 < Kc; k0 += 64) {
        #pragma unroll
        for (int i = 0; i < NL; ++i) { gload16(gp[i], dl[i]); gp[i] += 64; }
        __syncthreads();
        #pragma unroll
        for (int ks = 0; ks < 2; ++ks) {
            bf16x8 a_[MI], b_[4];
            #pragma unroll
            for (int mi = 0; mi < MI; ++mi) {
                const int ar = ar0 + mi * 16 + fl;
                const int byo = (ks * 64 + kunit) ^ ((ar & 7) << 4);
                a_[mi] = *reinterpret_cast<const bf16x8*>(
                    reinterpret_cast<const char*>(buf + ar * 64) + byo);
            }
            #pragma unroll
            for (int f = 0; f < 4; ++f) {
                const int br = bc0 + wn * 64 + f * 16 + fl;
                const int byo = (ks * 64 + kunit) ^ ((br & 7) << 4);
                b_[f] = *reinterpret_cast<const bf16x8*>(
                    reinterpret_cast<const char*>(buf + br * 64) + byo);
            }
            #pragma unroll
            for (int mi = 0; mi < MI; ++mi)
                #pragma unroll
                for (int f = 0; f < 4; ++f)
                    acc[mi][f] = __builtin_amdgcn_mfma_f32_16x16x32_bf16(
                        a_[mi], b_[f], acc[mi][f], 0, 0, 0);
        }
        __syncthreads();
    }

    if constexpr (KG > 1) {
        f32x4* red = reinterpret_cast<f32x4*>(smem);
        #pragma unroll
        for (int pass = 0; pass < NP; ++pass) {
            if (kg > 0) {
                #pragma unroll
                for (int f = 0; f < RC; ++f) {
                    const int fr = pass * RC + f;
                    red[(((kg - 1) * S + slot) * RC + f) * 64 + lane] =
                        acc[fr >> 2][fr & 3];
                }
            }
            __syncthreads();
            if (kg == 0) {
                #pragma unroll
                for (int q = 1; q < KG; ++q)
                    #pragma unroll
                    for (int f = 0; f < RC; ++f) {
                        const int fr = pass * RC + f;
                        f32x4 v = red[(((q - 1) * S + slot) * RC + f) * 64 + lane];
                        acc[fr >> 2][fr & 3][0] += v[0];
                        acc[fr >> 2][fr & 3][1] += v[1];
                        acc[fr >> 2][fr & 3][2] += v[2];
                        acc[fr >> 2][fr & 3][3] += v[3];
                    }
            }
            __syncthreads();
        }
    }

    if (kg != 0) return;
    const int j = ((c0 + wn * 64) >> 6) * 16 + fl;
    #pragma unroll
    for (int mi = 0; mi < MI; ++mi) {
        #pragma unroll
        for (int r = 0; r < 4; ++r) {
            const int m = m0 + wm * MI * 16 + mi * 16 + (lane >> 4) * 4 + r;
            if (m >= n) continue;
            const u16* gx = GXl + (size_t)m * 4096 + c0 + wn * 64 + fl;
            const float i_ = acc[mi][0][r] + h2f(__builtin_nontemporal_load(gx));
            const float f_ = acc[mi][1][r] + h2f(__builtin_nontemporal_load(gx + 16));
            const float g_ = acc[mi][2][r] + h2f(__builtin_nontemporal_load(gx + 32));
            const float o_ = acc[mi][3][r] + h2f(__builtin_nontemporal_load(gx + 48));
            const float cc = __builtin_nontemporal_load(cprev + (size_t)m * 1024 + j);
            const float cn = fsig(f_) * cc + fsig(i_) * ftanh(g_);
            const float hn = fsig(o_) * ftanh(cn);
            if (hnext)
                hnext[(size_t)(m >> 1) * 2048 + (m & 1) * 1024 + j] = f2bf(hn);
            if (!(m & 1))
                __builtin_nontemporal_store(cn, cnext + (size_t)(m >> 1) * 1024 + j);
            if (outp) { outp[j] = hn; outp[1024 + j] = cn; }
        }
    }
}

// ---------------------------------------------------------------- launcher
extern "C" void kernel_launch(void* const* d_in, const int* in_sizes, int n_in,
                              void* d_out, int out_size, void* d_ws, size_t ws_size,
                              hipStream_t stream) {
    const float* emb  = (const float*)d_in[0];
    const float* W_ih = (const float*)d_in[1];
    const float* W_hh = (const float*)d_in[2];
    const float* b_ih = (const float*)d_in[3];
    const float* b_hh = (const float*)d_in[4];
    float* out = (float*)d_out;

    char* p = (char*)d_ws;
    float* bge  = (float*)p;  p += 16384;
    u16* Wih_p  = (u16*)p;    p += (size_t)4096 * 1024 * 2;   //  8.4 MB
    u16* Whh_p  = (u16*)p;    p += (size_t)4096 * 2048 * 2;   // 16.8 MB
    u16* xb     = (u16*)p;    p += (size_t)4096 * 1024 * 2;   //  8.4 MB
    u16* GX     = (u16*)p;    p += (size_t)4096 * 4096 * 2;   // 33.6 MB (rows<2047 used)
    u16* Hcat   = (u16*)p;    p += (size_t)4096 * 2048 * 2;   // 16.8 MB
    float* cbA  = (float*)p;  p += (size_t)1024 * 1024 * 4;   //  4.2 MB
    float* cbB  = (float*)p;  p += (size_t)1024 * 1024 * 4;   //  4.2 MB

    // prep_a: xb + Wih_p + bge only (~67 MB traffic).
    prep_a<<<8207, 256, 0, stream>>>(W_ih, emb, b_ih, b_hh, Wih_p, xb, bge);

    #define OFF(k) (4096 - (2 << (k)))

    // GX GEMM (1024 blocks) + Whh packing (8192 blocks) in ONE dispatch:
    // packing's 100MB of BW hides under the compute-bound GEMM.
    gx_pack<<<9216, 256, 0, stream>>>(
        xb, Wih_p, bge, GX, Hcat + (size_t)OFF(10) * 2048, cbA, W_hh, Whh_p);

    const float* cprev = cbA;
    float* cbufs[2] = {cbB, cbA};
    int t = 0;
    for (int k = TREE_DEPTH - 2; k >= 0; --k) {
        const int n = 1 << k;
        const u16* A = Hcat + (size_t)OFF(k) * 2048;
        const u16* GXl = GX + (size_t)(n - 1) * 4096;
        u16* hnext = (k > 0) ? (Hcat + (size_t)OFF(k - 1) * 2048) : nullptr;
        float* cnext = cbufs[t];
        float* outp = (k == 0) ? out : nullptr;

        if (k == 10) {
            // BM=64, BN=128, KG=2, 256 thr: 512 blocks (2/CU).
            fused_level<4, 1, 2, 2><<<dim3(16, 32), 256, 0, stream>>>(
                A, Whh_p, GXl, cprev, hnext, cnext, outp, n);
        } else if (k == 9) {
            // BM=32, BN=128, KG=2, 256 thr: 512 blocks (2/CU).
            fused_level<2, 1, 2, 2><<<dim3(16, 32), 256, 0, stream>>>(
                A, Whh_p, GXl, cprev, hnext, cnext, outp, n);
        } else if (k == 8) {
            // BM=16, BN=64, KG=4, 256 thr: 1024 blocks (4/CU).
            fused_level<1, 1, 1, 4><<<dim3(16, 64), 256, 0, stream>>>(
                A, Whh_p, GXl, cprev, hnext, cnext, outp, n);
        } else {
            // BM=16, BN=64, KG=8, 512 thr: up to 512 blocks.
            const int gx = (n >= 16) ? n / 16 : 1;
            fused_level<1, 1, 1, 8><<<dim3(gx, 64), 512, 0, stream>>>(
                A, Whh_p, GXl, cprev, hnext, cnext, outp, n);
        }
        cprev = cnext; t ^= 1;
    }
}

// Round 22
// 220.983 us; speedup vs baseline: 1.0124x; 1.0124x over previous
//
#include <hip/hip_runtime.h>
#include <hip/hip_bf16.h>
#include <math.h>

// BinaryTreeLSTM — round 22: exact restore of the round-16 best (221.0 us).
// r17 (dbuf), r18 (256^2 8-wave), r19 (tail KSX), r20 (16-wave max-occ),
// r21 (pack overlap) all measured null-or-regress — this is the measured
// minimum configuration of this structure.
//
// Packed gate-interleaved column space: e = (j/16)*64 + g*16 + (j%16)
//   (orig W row g*2048+j). Wih_p[4096][1024], Whh_p[4096][2048] bf16,
//   XCD-affine 128-row tiles: tile (e>>7) written by blocks with b&7==(e>>7)%8.
// GX[4096][4096] fp16: rows 0..2046 = bf16(emb[node]) @ Wih_p^T + bge;
//   rows >= 2047 (level-11) consumed in-register by the gemm_gx epilogue.
// Hcat: level-k h-slab at row OFF(k)=4096-2^(k+1), 2^k rows x 2048 bf16.
// c compact: level k writes even-node c at row m>>1 (1024 f32); k-1 reads row m.

#define TREE_DEPTH 12

typedef unsigned short u16;
typedef unsigned int u32;
typedef __attribute__((ext_vector_type(8))) short bf16x8;
typedef __attribute__((ext_vector_type(4))) float f32x4;
typedef __attribute__((ext_vector_type(8))) unsigned short u16x8;
typedef __attribute__((ext_vector_type(2))) unsigned int u32x2;

__device__ __forceinline__ void gload16(const void* g, void* l) {
    __builtin_amdgcn_global_load_lds(
        (const __attribute__((address_space(1))) u32*)g,
        (__attribute__((address_space(3))) u32*)l, 16, 0, 0);
}

__device__ __forceinline__ u16 f2bf(float f) {
    __hip_bfloat16 h = __float2bfloat16(f);
    return *reinterpret_cast<u16*>(&h);
}
__device__ __forceinline__ u16 f2h(float f) {
    _Float16 h = (_Float16)f;
    return *reinterpret_cast<u16*>(&h);
}
__device__ __forceinline__ float h2f(u16 u) {
    _Float16 h;
    *reinterpret_cast<u16*>(&h) = u;
    return (float)h;
}
__device__ __forceinline__ float fsig(float x) {
    return 1.0f / (1.0f + __expf(-x));
}
__device__ __forceinline__ float ftanh(float x) {
    return 1.0f - 2.0f / (1.0f + __expf(2.0f * x));
}

// ---------------------------------------------------------------- prep
__global__ void prep(const float* __restrict__ Wih,
                     const float* __restrict__ Whh,
                     const float* __restrict__ emb,
                     const float* __restrict__ b_ih,
                     const float* __restrict__ b_hh,
                     u16* __restrict__ Wih_p, u16* __restrict__ Whh_p,
                     u16* __restrict__ xb, float* __restrict__ bge) {
    const int bid = blockIdx.x;
    if (bid < 12288) {
        const int b = bid & 4095;
        const int seg = bid >> 12;         // 0: ih, 1/2: hh halves
        const int x = b & 7, t = b >> 3;   // t in [0,512)
        const int e = ((t & 3) * 8 + x) * 128 + (t >> 2);  // (e>>7)%8 == x
        const int g = (e >> 4) & 3;
        const int j = (e >> 6) * 16 + (e & 15);
        const int wr = g * 2048 + j;
        const int col = threadIdx.x * 4;
        f32x4 v;
        u16* dst;
        if (seg == 0) {
            v = __builtin_nontemporal_load(
                (const f32x4*)(Wih + (size_t)wr * 1024 + col));
            dst = Wih_p + (size_t)e * 1024 + col;
        } else {
            v = __builtin_nontemporal_load(
                (const f32x4*)(Whh + (size_t)wr * 2048 + (seg - 1) * 1024 + col));
            dst = Whh_p + (size_t)e * 2048 + (seg - 1) * 1024 + col;
        }
        u32x2 p;
        p[0] = (u32)f2bf(v[0]) | ((u32)f2bf(v[1]) << 16);
        p[1] = (u32)f2bf(v[2]) | ((u32)f2bf(v[3]) << 16);
        *reinterpret_cast<u32x2*>(dst) = p;
    } else if (bid < 16383) {
        size_t idx = ((size_t)(bid - 12288) * 256 + threadIdx.x) * 4;
        f32x4 v = __builtin_nontemporal_load((const f32x4*)(emb + idx));
        u32x2 p;
        p[0] = (u32)f2bf(v[0]) | ((u32)f2bf(v[1]) << 16);
        p[1] = (u32)f2bf(v[2]) | ((u32)f2bf(v[3]) << 16);
        *reinterpret_cast<u32x2*>(xb + idx) = p;
    } else {
        int e = (bid - 16383) * 256 + threadIdx.x;   // 0..4095 packed order
        int g = (e >> 4) & 3;
        int j = (e >> 6) * 16 + (e & 15);
        int r = g * 2048 + j;
        bge[e] = b_ih[r] + b_hh[r];
    }
}

// ---------------------------------------------------------------- GX GEMM
// Rows < 2047: GX fp16 (LDS-staged store). Rows >= 2047: level-11 cell.
// 128x128 tile, 4 waves, BK=64 swizzled (r15-proven).
__global__ __launch_bounds__(256) void gemm_gx(
    const u16* __restrict__ xb, const u16* __restrict__ Wp,
    const float* __restrict__ bge, u16* __restrict__ GX,
    u16* __restrict__ hdst, float* __restrict__ cdst)
{
    __shared__ u16 smem[128 * 140];   // staging uses [0, 256*64) u16

    const int gx_ = gridDim.x;   // 32
    int b = blockIdx.x + gx_ * blockIdx.y;
    const int x = b & 7, t = b >> 3;
    const int ct = (t & 3) * 8 + x;
    const int mt = t >> 2;
    const int m0 = mt * 128, c0 = ct * 128;

    const int tid = threadIdx.x, lane = tid & 63, w = tid >> 6;
    const int wr = (w >> 1) * 64, wc = (w & 1) * 64;

    f32x4 acc[4][4];
    #pragma unroll
    for (int i = 0; i < 4; ++i)
        #pragma unroll
        for (int j = 0; j < 4; ++j)
            acc[i][j] = f32x4{0.f, 0.f, 0.f, 0.f};

    const u16* gp[8];
    u16* dl[8];
    #pragma unroll
    for (int i = 0; i < 8; ++i) {
        const int s = tid + i * 256;
        const int r = s >> 3;
        const int o = (s & 7) * 16;
        const int ke = (o ^ ((r & 7) << 4)) >> 1;   // element offset 0..63
        gp[i] = (r < 128) ? xb + (size_t)(m0 + r) * 1024 + ke
                          : Wp + (size_t)(c0 + r - 128) * 1024 + ke;
        dl[i] = smem + s * 8;
    }

    const int fl = lane & 15;
    const int kunit = (lane >> 4) * 16;   // byte offset of fragment in k-chunk

    for (int k0 = 0; k0 < 1024; k0 += 64) {
        #pragma unroll
        for (int i = 0; i < 8; ++i) { gload16(gp[i], dl[i]); gp[i] += 64; }
        __syncthreads();
        #pragma unroll
        for (int ks = 0; ks < 2; ++ks) {
            bf16x8 a_[4], b_[4];
            #pragma unroll
            for (int i = 0; i < 4; ++i) {
                const int ar = wr + i * 16 + fl;
                const int byo = (ks * 64 + kunit) ^ ((ar & 7) << 4);
                a_[i] = *reinterpret_cast<const bf16x8*>(
                    reinterpret_cast<const char*>(smem + ar * 64) + byo);
            }
            #pragma unroll
            for (int j = 0; j < 4; ++j) {
                const int br = 128 + wc + j * 16 + fl;
                const int byo = (ks * 64 + kunit) ^ ((br & 7) << 4);
                b_[j] = *reinterpret_cast<const bf16x8*>(
                    reinterpret_cast<const char*>(smem + br * 64) + byo);
            }
            #pragma unroll
            for (int i = 0; i < 4; ++i)
                #pragma unroll
                for (int j = 0; j < 4; ++j)
                    acc[i][j] = __builtin_amdgcn_mfma_f32_16x16x32_bf16(
                        a_[i], b_[j], acc[i][j], 0, 0, 0);
        }
        __syncthreads();
    }

    const int rg = (lane >> 4) * 4;
    if (m0 < 2047) {
        #pragma unroll
        for (int i = 0; i < 4; ++i)
            #pragma unroll
            for (int j = 0; j < 4; ++j) {
                const float bv = bge[c0 + wc + j * 16 + fl];
                #pragma unroll
                for (int r = 0; r < 4; ++r)
                    smem[(wr + i * 16 + rg + r) * 140 + (wc + j * 16 + fl)] =
                        f2h(acc[i][j][r] + bv);
            }
        __syncthreads();
        const int row_ = tid >> 4, chunk = tid & 15;
        #pragma unroll
        for (int it = 0; it < 8; ++it) {
            const int row = it * 16 + row_;
            if (m0 + row < 2047) {
                u16x8 v = *reinterpret_cast<const u16x8*>(
                    &smem[row * 140 + chunk * 8]);
                __builtin_nontemporal_store(
                    v, (u16x8*)(GX + (size_t)(m0 + row) * 4096 + c0 + chunk * 8));
            }
        }
    }
    if (m0 + 127 >= 2047) {
        const int jj = ((c0 + wc) >> 6) * 16 + fl;
        const float bi  = bge[c0 + wc + fl];
        const float bgg = bge[c0 + wc + 32 + fl];
        const float bo  = bge[c0 + wc + 48 + fl];
        #pragma unroll
        for (int i = 0; i < 4; ++i) {
            #pragma unroll
            for (int r = 0; r < 4; ++r) {
                const int m = m0 + wr + i * 16 + rg + r;
                if (m < 2047 || m >= 4095) continue;
                const int mm = m - 2047;
                const float cn = fsig(acc[i][0][r] + bi) * ftanh(acc[i][2][r] + bgg);
                const float hn = fsig(acc[i][3][r] + bo) * ftanh(cn);
                hdst[(size_t)(mm >> 1) * 2048 + (mm & 1) * 1024 + jj] = f2bf(hn);
                if (!(mm & 1))
                    cdst[(size_t)(mm >> 1) * 1024 + jj] = cn;
            }
        }
    }
}

// ---------------------------------------------------------------- fused level
// gates = A(h_cat) @ Whh_p^T + GX[node]; K=2048 split KG ways in-block.
// BK=64, both-sides-swizzled LDS (128B rows, byte ^= (row&7)<<4).
template <int MI, int MW, int NW, int KG>
__global__ __launch_bounds__(MW* NW* KG * 64) void fused_level(
    const u16* __restrict__ A, const u16* __restrict__ Wp,
    const u16* __restrict__ GXl, const float* __restrict__ cprev,
    u16* __restrict__ hnext, float* __restrict__ cnext,
    float* __restrict__ outp, int n)
{
    constexpr int BM = MI * 16 * MW;
    constexpr int BN = NW * 64;
    constexpr int S = MW * NW;
    constexpr int NFR = MI * 4;
    constexpr int RC = NFR > 8 ? 8 : NFR;
    constexpr int NP = NFR / RC;
    constexpr int ROWS = BM + BN;
    constexpr int SLOTS = ROWS * 8;       // 16B slots per BK=64 step
    constexpr int GT = S * 64;
    constexpr int NL = SLOTS / GT;
    static_assert(SLOTS % GT == 0, "slot mapping must be exact");
    constexpr int STG = KG * ROWS * 128;
    constexpr int REDB = (KG > 1) ? (KG - 1) * S * RC * 64 * 16 : 0;
    constexpr int SMEM = STG > REDB ? STG : REDB;
    __shared__ __align__(16) char smem[SMEM];

    const int gx_ = gridDim.x;
    int b = blockIdx.x + gx_ * blockIdx.y;
    const int x = b & 7;
    int t = b >> 3;
    int ct, mt;
    if constexpr (NW == 2) {
        ct = (t & 3) * 8 + x; mt = t >> 2;
    } else {
        const int lo = t & 1; t >>= 1;
        ct = ((t & 3) * 8 + x) * 2 + lo; mt = t >> 2;
    }
    const int m0 = mt * BM;
    const int c0 = ct * BN;

    const int tid = threadIdx.x;
    const int lane = tid & 63;
    const int w = tid >> 6;
    const int kg = w / S;
    const int slot = w % S;
    const int wm = slot / NW;
    const int wn = slot % NW;

    const int Kc = 2048 / KG;
    const int kbeg = kg * Kc;

    u16* buf = (u16*)smem + (size_t)kg * ROWS * 64;

    const int gtid = slot * 64 + lane;
    const u16* gp[NL];
    u16* dl[NL];
    #pragma unroll
    for (int i = 0; i < NL; ++i) {
        const int s = gtid + i * GT;
        const int r = s >> 3;
        const int o = (s & 7) * 16;
        const int ke = (o ^ ((r & 7) << 4)) >> 1;   // element 0..63
        if (r < BM) {
            int ar = m0 + r;
            if (ar >= n) ar = n - 1;
            gp[i] = A + (size_t)ar * 2048 + kbeg + ke;
        } else {
            gp[i] = Wp + (size_t)(c0 + r - BM) * 2048 + kbeg + ke;
        }
        dl[i] = buf + s * 8;
    }

    f32x4 acc[MI][4];
    #pragma unroll
    for (int mi = 0; mi < MI; ++mi)
        #pragma unroll
        for (int f = 0; f < 4; ++f)
            acc[mi][f] = f32x4{0.f, 0.f, 0.f, 0.f};

    const int fl = lane & 15;
    const int kunit = (lane >> 4) * 16;
    const int ar0 = wm * MI * 16;
    const int bc0 = BM;

    for (int k0 = 0; k0 < Kc; k0 += 64) {
        #pragma unroll
        for (int i = 0; i < NL; ++i) { gload16(gp[i], dl[i]); gp[i] += 64; }
        __syncthreads();
        #pragma unroll
        for (int ks = 0; ks < 2; ++ks) {
            bf16x8 a_[MI], b_[4];
            #pragma unroll
            for (int mi = 0; mi < MI; ++mi) {
                const int ar = ar0 + mi * 16 + fl;
                const int byo = (ks * 64 + kunit) ^ ((ar & 7) << 4);
                a_[mi] = *reinterpret_cast<const bf16x8*>(
                    reinterpret_cast<const char*>(buf + ar * 64) + byo);
            }
            #pragma unroll
            for (int f = 0; f < 4; ++f) {
                const int br = bc0 + wn * 64 + f * 16 + fl;
                const int byo = (ks * 64 + kunit) ^ ((br & 7) << 4);
                b_[f] = *reinterpret_cast<const bf16x8*>(
                    reinterpret_cast<const char*>(buf + br * 64) + byo);
            }
            #pragma unroll
            for (int mi = 0; mi < MI; ++mi)
                #pragma unroll
                for (int f = 0; f < 4; ++f)
                    acc[mi][f] = __builtin_amdgcn_mfma_f32_16x16x32_bf16(
                        a_[mi], b_[f], acc[mi][f], 0, 0, 0);
        }
        __syncthreads();
    }

    if constexpr (KG > 1) {
        f32x4* red = reinterpret_cast<f32x4*>(smem);
        #pragma unroll
        for (int pass = 0; pass < NP; ++pass) {
            if (kg > 0) {
                #pragma unroll
                for (int f = 0; f < RC; ++f) {
                    const int fr = pass * RC + f;
                    red[(((kg - 1) * S + slot) * RC + f) * 64 + lane] =
                        acc[fr >> 2][fr & 3];
                }
            }
            __syncthreads();
            if (kg == 0) {
                #pragma unroll
                for (int q = 1; q < KG; ++q)
                    #pragma unroll
                    for (int f = 0; f < RC; ++f) {
                        const int fr = pass * RC + f;
                        f32x4 v = red[(((q - 1) * S + slot) * RC + f) * 64 + lane];
                        acc[fr >> 2][fr & 3][0] += v[0];
                        acc[fr >> 2][fr & 3][1] += v[1];
                        acc[fr >> 2][fr & 3][2] += v[2];
                        acc[fr >> 2][fr & 3][3] += v[3];
                    }
            }
            __syncthreads();
        }
    }

    if (kg != 0) return;
    const int j = ((c0 + wn * 64) >> 6) * 16 + fl;
    #pragma unroll
    for (int mi = 0; mi < MI; ++mi) {
        #pragma unroll
        for (int r = 0; r < 4; ++r) {
            const int m = m0 + wm * MI * 16 + mi * 16 + (lane >> 4) * 4 + r;
            if (m >= n) continue;
            const u16* gx = GXl + (size_t)m * 4096 + c0 + wn * 64 + fl;
            const float i_ = acc[mi][0][r] + h2f(__builtin_nontemporal_load(gx));
            const float f_ = acc[mi][1][r] + h2f(__builtin_nontemporal_load(gx + 16));
            const float g_ = acc[mi][2][r] + h2f(__builtin_nontemporal_load(gx + 32));
            const float o_ = acc[mi][3][r] + h2f(__builtin_nontemporal_load(gx + 48));
            const float cc = __builtin_nontemporal_load(cprev + (size_t)m * 1024 + j);
            const float cn = fsig(f_) * cc + fsig(i_) * ftanh(g_);
            const float hn = fsig(o_) * ftanh(cn);
            if (hnext)
                hnext[(size_t)(m >> 1) * 2048 + (m & 1) * 1024 + j] = f2bf(hn);
            if (!(m & 1))
                __builtin_nontemporal_store(cn, cnext + (size_t)(m >> 1) * 1024 + j);
            if (outp) { outp[j] = hn; outp[1024 + j] = cn; }
        }
    }
}

// ---------------------------------------------------------------- launcher
extern "C" void kernel_launch(void* const* d_in, const int* in_sizes, int n_in,
                              void* d_out, int out_size, void* d_ws, size_t ws_size,
                              hipStream_t stream) {
    const float* emb  = (const float*)d_in[0];
    const float* W_ih = (const float*)d_in[1];
    const float* W_hh = (const float*)d_in[2];
    const float* b_ih = (const float*)d_in[3];
    const float* b_hh = (const float*)d_in[4];
    float* out = (float*)d_out;

    char* p = (char*)d_ws;
    float* bge  = (float*)p;  p += 16384;
    u16* Wih_p  = (u16*)p;    p += (size_t)4096 * 1024 * 2;   //  8.4 MB
    u16* Whh_p  = (u16*)p;    p += (size_t)4096 * 2048 * 2;   // 16.8 MB
    u16* xb     = (u16*)p;    p += (size_t)4096 * 1024 * 2;   //  8.4 MB
    u16* GX     = (u16*)p;    p += (size_t)4096 * 4096 * 2;   // 33.6 MB (rows<2047 used)
    u16* Hcat   = (u16*)p;    p += (size_t)4096 * 2048 * 2;   // 16.8 MB
    float* cbA  = (float*)p;  p += (size_t)1024 * 1024 * 4;   //  4.2 MB
    float* cbB  = (float*)p;  p += (size_t)1024 * 1024 * 4;   //  4.2 MB

    prep<<<16399, 256, 0, stream>>>(W_ih, W_hh, emb, b_ih, b_hh,
                                    Wih_p, Whh_p, xb, bge);

    #define OFF(k) (4096 - (2 << (k)))

    // GX (rows < 2047) + fused level-11 cell (rows >= 2047).
    gemm_gx<<<dim3(32, 32), 256, 0, stream>>>(
        xb, Wih_p, bge, GX, Hcat + (size_t)OFF(10) * 2048, cbA);

    const float* cprev = cbA;
    float* cbufs[2] = {cbB, cbA};
    int t = 0;
    for (int k = TREE_DEPTH - 2; k >= 0; --k) {
        const int n = 1 << k;
        const u16* A = Hcat + (size_t)OFF(k) * 2048;
        const u16* GXl = GX + (size_t)(n - 1) * 4096;
        u16* hnext = (k > 0) ? (Hcat + (size_t)OFF(k - 1) * 2048) : nullptr;
        float* cnext = cbufs[t];
        float* outp = (k == 0) ? out : nullptr;

        if (k == 10) {
            // BM=64, BN=128, KG=2, 256 thr: 512 blocks (2/CU).
            fused_level<4, 1, 2, 2><<<dim3(16, 32), 256, 0, stream>>>(
                A, Whh_p, GXl, cprev, hnext, cnext, outp, n);
        } else if (k == 9) {
            // BM=32, BN=128, KG=2, 256 thr: 512 blocks (2/CU).
            fused_level<2, 1, 2, 2><<<dim3(16, 32), 256, 0, stream>>>(
                A, Whh_p, GXl, cprev, hnext, cnext, outp, n);
        } else if (k == 8) {
            // BM=16, BN=64, KG=4, 256 thr: 1024 blocks (4/CU).
            fused_level<1, 1, 1, 4><<<dim3(16, 64), 256, 0, stream>>>(
                A, Whh_p, GXl, cprev, hnext, cnext, outp, n);
        } else {
            // BM=16, BN=64, KG=8, 512 thr: up to 512 blocks.
            const int gx = (n >= 16) ? n / 16 : 1;
            fused_level<1, 1, 1, 8><<<dim3(gx, 64), 512, 0, stream>>>(
                A, Whh_p, GXl, cprev, hnext, cnext, outp, n);
        }
        cprev = cnext; t ^= 1;
    }
}

// Round 23
// 220.953 us; speedup vs baseline: 1.0126x; 1.0001x over previous
//
#include <hip/hip_runtime.h>
#include <hip/hip_bf16.h>
#include <math.h>

// BinaryTreeLSTM — round 23: r22 baseline + pack/GEMM overlap retry with
// the r21 failure fixed: Whh packer blocks come FIRST in the combined
// dispatch (bid [0,8192)), GEMM blocks after (bid [8192,9216)) — packers
// drain fast and their BW overlaps the non-BW-bound GEMM, instead of
// queuing behind it (r21's measured serialization).
//
// Packed gate-interleaved column space: e = (j/16)*64 + g*16 + (j%16)
//   (orig W row g*2048+j). Wih_p[4096][1024], Whh_p[4096][2048] bf16,
//   XCD-affine 128-row tiles.
// GX[4096][4096] fp16: rows 0..2046 = bf16(emb[node]) @ Wih_p^T + bge;
//   rows >= 2047 (level-11) consumed in-register by the gemm epilogue.
// Hcat: level-k h-slab at row OFF(k)=4096-2^(k+1), 2^k rows x 2048 bf16.
// c compact: level k writes even-node c at row m>>1 (1024 f32); k-1 reads row m.

#define TREE_DEPTH 12

typedef unsigned short u16;
typedef unsigned int u32;
typedef __attribute__((ext_vector_type(8))) short bf16x8;
typedef __attribute__((ext_vector_type(4))) float f32x4;
typedef __attribute__((ext_vector_type(8))) unsigned short u16x8;
typedef __attribute__((ext_vector_type(2))) unsigned int u32x2;

__device__ __forceinline__ void gload16(const void* g, void* l) {
    __builtin_amdgcn_global_load_lds(
        (const __attribute__((address_space(1))) u32*)g,
        (__attribute__((address_space(3))) u32*)l, 16, 0, 0);
}

__device__ __forceinline__ u16 f2bf(float f) {
    __hip_bfloat16 h = __float2bfloat16(f);
    return *reinterpret_cast<u16*>(&h);
}
__device__ __forceinline__ u16 f2h(float f) {
    _Float16 h = (_Float16)f;
    return *reinterpret_cast<u16*>(&h);
}
__device__ __forceinline__ float h2f(u16 u) {
    _Float16 h;
    *reinterpret_cast<u16*>(&h) = u;
    return (float)h;
}
__device__ __forceinline__ float fsig(float x) {
    return 1.0f / (1.0f + __expf(-x));
}
__device__ __forceinline__ float ftanh(float x) {
    return 1.0f - 2.0f / (1.0f + __expf(2.0f * x));
}

// ---------------------------------------------------------------- prep_a
// Blocks [0,4096): pack W_ih -> Wih_p; [4096,8191): emb -> xb bf16;
// [8191,8207): fuse bias into packed-e order.
__global__ void prep_a(const float* __restrict__ Wih,
                       const float* __restrict__ emb,
                       const float* __restrict__ b_ih,
                       const float* __restrict__ b_hh,
                       u16* __restrict__ Wih_p,
                       u16* __restrict__ xb, float* __restrict__ bge) {
    const int bid = blockIdx.x;
    if (bid < 4096) {
        const int b = bid;
        const int x = b & 7, t = b >> 3;   // t in [0,512)
        const int e = ((t & 3) * 8 + x) * 128 + (t >> 2);  // (e>>7)%8 == x
        const int g = (e >> 4) & 3;
        const int j = (e >> 6) * 16 + (e & 15);
        const int wr = g * 2048 + j;
        const int col = threadIdx.x * 4;
        f32x4 v = __builtin_nontemporal_load(
            (const f32x4*)(Wih + (size_t)wr * 1024 + col));
        u32x2 p;
        p[0] = (u32)f2bf(v[0]) | ((u32)f2bf(v[1]) << 16);
        p[1] = (u32)f2bf(v[2]) | ((u32)f2bf(v[3]) << 16);
        *reinterpret_cast<u32x2*>(Wih_p + (size_t)e * 1024 + col) = p;
    } else if (bid < 8191) {
        size_t idx = ((size_t)(bid - 4096) * 256 + threadIdx.x) * 4;
        f32x4 v = __builtin_nontemporal_load((const f32x4*)(emb + idx));
        u32x2 p;
        p[0] = (u32)f2bf(v[0]) | ((u32)f2bf(v[1]) << 16);
        p[1] = (u32)f2bf(v[2]) | ((u32)f2bf(v[3]) << 16);
        *reinterpret_cast<u32x2*>(xb + idx) = p;
    } else {
        int e = (bid - 8191) * 256 + threadIdx.x;   // 0..4095 packed order
        int g = (e >> 4) & 3;
        int j = (e >> 6) * 16 + (e & 15);
        int r = g * 2048 + j;
        bge[e] = b_ih[r] + b_hh[r];
    }
}

// ---------------------------------------------------------------- packW + GX
// Blocks [0,8192): pack W_hh -> Whh_p (launch FIRST; overlaps GEMM).
// Blocks [8192,9216): r16-proven GEMM (128x128, 4 waves, BK=64 swizzled).
//   Rows < 2047: GX fp16 (LDS-staged store). Rows >= 2047: L11 cell.
__global__ __launch_bounds__(256) void gx_pack(
    const u16* __restrict__ xb, const u16* __restrict__ Wp,
    const float* __restrict__ bge, u16* __restrict__ GX,
    u16* __restrict__ hdst, float* __restrict__ cdst,
    const float* __restrict__ Whh_f, u16* __restrict__ Whh_p)
{
    __shared__ u16 smem[128 * 140];   // staging uses [0, 256*64) u16

    const int bid = blockIdx.x;
    if (bid < 8192) {
        // ---- Whh packer block (tiny, drains fast)
        const int seg = bid >> 12;          // 0/1: low/high K half
        const int b = bid & 4095;
        const int x = b & 7, t = b >> 3;
        const int e = ((t & 3) * 8 + x) * 128 + (t >> 2);
        const int g = (e >> 4) & 3;
        const int j = (e >> 6) * 16 + (e & 15);
        const int wr = g * 2048 + j;
        const int col = threadIdx.x * 4;
        f32x4 v = __builtin_nontemporal_load(
            (const f32x4*)(Whh_f + (size_t)wr * 2048 + seg * 1024 + col));
        u32x2 p;
        p[0] = (u32)f2bf(v[0]) | ((u32)f2bf(v[1]) << 16);
        p[1] = (u32)f2bf(v[2]) | ((u32)f2bf(v[3]) << 16);
        *reinterpret_cast<u32x2*>(Whh_p + (size_t)e * 2048 + seg * 1024 + col) = p;
        return;
    }

    // ---- GEMM block (r16/r22-proven, bit-identical math)
    const int bb = bid - 8192;              // 0..1023
    const int x = bb & 7, t = bb >> 3;
    const int ct = (t & 3) * 8 + x;
    const int mt = t >> 2;
    const int m0 = mt * 128, c0 = ct * 128;

    const int tid = threadIdx.x, lane = tid & 63, w = tid >> 6;
    const int wr = (w >> 1) * 64, wc = (w & 1) * 64;

    f32x4 acc[4][4];
    #pragma unroll
    for (int i = 0; i < 4; ++i)
        #pragma unroll
        for (int j = 0; j < 4; ++j)
            acc[i][j] = f32x4{0.f, 0.f, 0.f, 0.f};

    const u16* gp[8];
    u16* dl[8];
    #pragma unroll
    for (int i = 0; i < 8; ++i) {
        const int s = tid + i * 256;
        const int r = s >> 3;
        const int o = (s & 7) * 16;
        const int ke = (o ^ ((r & 7) << 4)) >> 1;   // element offset 0..63
        gp[i] = (r < 128) ? xb + (size_t)(m0 + r) * 1024 + ke
                          : Wp + (size_t)(c0 + r - 128) * 1024 + ke;
        dl[i] = smem + s * 8;
    }

    const int fl = lane & 15;
    const int kunit = (lane >> 4) * 16;   // byte offset of fragment in k-chunk

    for (int k0 = 0; k0 < 1024; k0 += 64) {
        #pragma unroll
        for (int i = 0; i < 8; ++i) { gload16(gp[i], dl[i]); gp[i] += 64; }
        __syncthreads();
        #pragma unroll
        for (int ks = 0; ks < 2; ++ks) {
            bf16x8 a_[4], b_[4];
            #pragma unroll
            for (int i = 0; i < 4; ++i) {
                const int ar = wr + i * 16 + fl;
                const int byo = (ks * 64 + kunit) ^ ((ar & 7) << 4);
                a_[i] = *reinterpret_cast<const bf16x8*>(
                    reinterpret_cast<const char*>(smem + ar * 64) + byo);
            }
            #pragma unroll
            for (int j = 0; j < 4; ++j) {
                const int br = 128 + wc + j * 16 + fl;
                const int byo = (ks * 64 + kunit) ^ ((br & 7) << 4);
                b_[j] = *reinterpret_cast<const bf16x8*>(
                    reinterpret_cast<const char*>(smem + br * 64) + byo);
            }
            #pragma unroll
            for (int i = 0; i < 4; ++i)
                #pragma unroll
                for (int j = 0; j < 4; ++j)
                    acc[i][j] = __builtin_amdgcn_mfma_f32_16x16x32_bf16(
                        a_[i], b_[j], acc[i][j], 0, 0, 0);
        }
        __syncthreads();
    }

    const int rg = (lane >> 4) * 4;
    if (m0 < 2047) {
        #pragma unroll
        for (int i = 0; i < 4; ++i)
            #pragma unroll
            for (int j = 0; j < 4; ++j) {
                const float bv = bge[c0 + wc + j * 16 + fl];
                #pragma unroll
                for (int r = 0; r < 4; ++r)
                    smem[(wr + i * 16 + rg + r) * 140 + (wc + j * 16 + fl)] =
                        f2h(acc[i][j][r] + bv);
            }
        __syncthreads();
        const int row_ = tid >> 4, chunk = tid & 15;
        #pragma unroll
        for (int it = 0; it < 8; ++it) {
            const int row = it * 16 + row_;
            if (m0 + row < 2047) {
                u16x8 v = *reinterpret_cast<const u16x8*>(
                    &smem[row * 140 + chunk * 8]);
                __builtin_nontemporal_store(
                    v, (u16x8*)(GX + (size_t)(m0 + row) * 4096 + c0 + chunk * 8));
            }
        }
    }
    if (m0 + 127 >= 2047) {
        const int jj = ((c0 + wc) >> 6) * 16 + fl;
        const float bi  = bge[c0 + wc + fl];
        const float bgg = bge[c0 + wc + 32 + fl];
        const float bo  = bge[c0 + wc + 48 + fl];
        #pragma unroll
        for (int i = 0; i < 4; ++i) {
            #pragma unroll
            for (int r = 0; r < 4; ++r) {
                const int m = m0 + wr + i * 16 + rg + r;
                if (m < 2047 || m >= 4095) continue;
                const int mm = m - 2047;
                const float cn = fsig(acc[i][0][r] + bi) * ftanh(acc[i][2][r] + bgg);
                const float hn = fsig(acc[i][3][r] + bo) * ftanh(cn);
                hdst[(size_t)(mm >> 1) * 2048 + (mm & 1) * 1024 + jj] = f2bf(hn);
                if (!(mm & 1))
                    cdst[(size_t)(mm >> 1) * 1024 + jj] = cn;
            }
        }
    }
}

// ---------------------------------------------------------------- fused level
// gates = A(h_cat) @ Whh_p^T + GX[node]; K=2048 split KG ways in-block.
// BK=64, both-sides-swizzled LDS (r16-proven, unchanged).
template <int MI, int MW, int NW, int KG>
__global__ __launch_bounds__(MW* NW* KG * 64) void fused_level(
    const u16* __restrict__ A, const u16* __restrict__ Wp,
    const u16* __restrict__ GXl, const float* __restrict__ cprev,
    u16* __restrict__ hnext, float* __restrict__ cnext,
    float* __restrict__ outp, int n)
{
    constexpr int BM = MI * 16 * MW;
    constexpr int BN = NW * 64;
    constexpr int S = MW * NW;
    constexpr int NFR = MI * 4;
    constexpr int RC = NFR > 8 ? 8 : NFR;
    constexpr int NP = NFR / RC;
    constexpr int ROWS = BM + BN;
    constexpr int SLOTS = ROWS * 8;       // 16B slots per BK=64 step
    constexpr int GT = S * 64;
    constexpr int NL = SLOTS / GT;
    static_assert(SLOTS % GT == 0, "slot mapping must be exact");
    constexpr int STG = KG * ROWS * 128;
    constexpr int REDB = (KG > 1) ? (KG - 1) * S * RC * 64 * 16 : 0;
    constexpr int SMEM = STG > REDB ? STG : REDB;
    __shared__ __align__(16) char smem[SMEM];

    const int gx_ = gridDim.x;
    int b = blockIdx.x + gx_ * blockIdx.y;
    const int x = b & 7;
    int t = b >> 3;
    int ct, mt;
    if constexpr (NW == 2) {
        ct = (t & 3) * 8 + x; mt = t >> 2;
    } else {
        const int lo = t & 1; t >>= 1;
        ct = ((t & 3) * 8 + x) * 2 + lo; mt = t >> 2;
    }
    const int m0 = mt * BM;
    const int c0 = ct * BN;

    const int tid = threadIdx.x;
    const int lane = tid & 63;
    const int w = tid >> 6;
    const int kg = w / S;
    const int slot = w % S;
    const int wm = slot / NW;
    const int wn = slot % NW;

    const int Kc = 2048 / KG;
    const int kbeg = kg * Kc;

    u16* buf = (u16*)smem + (size_t)kg * ROWS * 64;

    const int gtid = slot * 64 + lane;
    const u16* gp[NL];
    u16* dl[NL];
    #pragma unroll
    for (int i = 0; i < NL; ++i) {
        const int s = gtid + i * GT;
        const int r = s >> 3;
        const int o = (s & 7) * 16;
        const int ke = (o ^ ((r & 7) << 4)) >> 1;   // element 0..63
        if (r < BM) {
            int ar = m0 + r;
            if (ar >= n) ar = n - 1;
            gp[i] = A + (size_t)ar * 2048 + kbeg + ke;
        } else {
            gp[i] = Wp + (size_t)(c0 + r - BM) * 2048 + kbeg + ke;
        }
        dl[i] = buf + s * 8;
    }

    f32x4 acc[MI][4];
    #pragma unroll
    for (int mi = 0; mi < MI; ++mi)
        #pragma unroll
        for (int f = 0; f < 4; ++f)
            acc[mi][f] = f32x4{0.f, 0.f, 0.f, 0.f};

    const int fl = lane & 15;
    const int kunit = (lane >> 4) * 16;
    const int ar0 = wm * MI * 16;
    const int bc0 = BM;

    for (int k0 = 0; k0 < Kc; k0 += 64) {
        #pragma unroll
        for (int i = 0; i < NL; ++i) { gload16(gp[i], dl[i]); gp[i] += 64; }
        __syncthreads();
        #pragma unroll
        for (int ks = 0; ks < 2; ++ks) {
            bf16x8 a_[MI], b_[4];
            #pragma unroll
            for (int mi = 0; mi < MI; ++mi) {
                const int ar = ar0 + mi * 16 + fl;
                const int byo = (ks * 64 + kunit) ^ ((ar & 7) << 4);
                a_[mi] = *reinterpret_cast<const bf16x8*>(
                    reinterpret_cast<const char*>(buf + ar * 64) + byo);
            }
            #pragma unroll
            for (int f = 0; f < 4; ++f) {
                const int br = bc0 + wn * 64 + f * 16 + fl;
                const int byo = (ks * 64 + kunit) ^ ((br & 7) << 4);
                b_[f] = *reinterpret_cast<const bf16x8*>(
                    reinterpret_cast<const char*>(buf + br * 64) + byo);
            }
            #pragma unroll
            for (int mi = 0; mi < MI; ++mi)
                #pragma unroll
                for (int f = 0; f < 4; ++f)
                    acc[mi][f] = __builtin_amdgcn_mfma_f32_16x16x32_bf16(
                        a_[mi], b_[f], acc[mi][f], 0, 0, 0);
        }
        __syncthreads();
    }

    if constexpr (KG > 1) {
        f32x4* red = reinterpret_cast<f32x4*>(smem);
        #pragma unroll
        for (int pass = 0; pass < NP; ++pass) {
            if (kg > 0) {
                #pragma unroll
                for (int f = 0; f < RC; ++f) {
                    const int fr = pass * RC + f;
                    red[(((kg - 1) * S + slot) * RC + f) * 64 + lane] =
                        acc[fr >> 2][fr & 3];
                }
            }
            __syncthreads();
            if (kg == 0) {
                #pragma unroll
                for (int q = 1; q < KG; ++q)
                    #pragma unroll
                    for (int f = 0; f < RC; ++f) {
                        const int fr = pass * RC + f;
                        f32x4 v = red[(((q - 1) * S + slot) * RC + f) * 64 + lane];
                        acc[fr >> 2][fr & 3][0] += v[0];
                        acc[fr >> 2][fr & 3][1] += v[1];
                        acc[fr >> 2][fr & 3][2] += v[2];
                        acc[fr >> 2][fr & 3][3] += v[3];
                    }
            }
            __syncthreads();
        }
    }

    if (kg != 0) return;
    const int j = ((c0 + wn * 64) >> 6) * 16 + fl;
    #pragma unroll
    for (int mi = 0; mi < MI; ++mi) {
        #pragma unroll
        for (int r = 0; r < 4; ++r) {
            const int m = m0 + wm * MI * 16 + mi * 16 + (lane >> 4) * 4 + r;
            if (m >= n) continue;
            const u16* gx = GXl + (size_t)m * 4096 + c0 + wn * 64 + fl;
            const float i_ = acc[mi][0][r] + h2f(__builtin_nontemporal_load(gx));
            const float f_ = acc[mi][1][r] + h2f(__builtin_nontemporal_load(gx + 16));
            const float g_ = acc[mi][2][r] + h2f(__builtin_nontemporal_load(gx + 32));
            const float o_ = acc[mi][3][r] + h2f(__builtin_nontemporal_load(gx + 48));
            const float cc = __builtin_nontemporal_load(cprev + (size_t)m * 1024 + j);
            const float cn = fsig(f_) * cc + fsig(i_) * ftanh(g_);
            const float hn = fsig(o_) * ftanh(cn);
            if (hnext)
                hnext[(size_t)(m >> 1) * 2048 + (m & 1) * 1024 + j] = f2bf(hn);
            if (!(m & 1))
                __builtin_nontemporal_store(cn, cnext + (size_t)(m >> 1) * 1024 + j);
            if (outp) { outp[j] = hn; outp[1024 + j] = cn; }
        }
    }
}

// ---------------------------------------------------------------- launcher
extern "C" void kernel_launch(void* const* d_in, const int* in_sizes, int n_in,
                              void* d_out, int out_size, void* d_ws, size_t ws_size,
                              hipStream_t stream) {
    const float* emb  = (const float*)d_in[0];
    const float* W_ih = (const float*)d_in[1];
    const float* W_hh = (const float*)d_in[2];
    const float* b_ih = (const float*)d_in[3];
    const float* b_hh = (const float*)d_in[4];
    float* out = (float*)d_out;

    char* p = (char*)d_ws;
    float* bge  = (float*)p;  p += 16384;
    u16* Wih_p  = (u16*)p;    p += (size_t)4096 * 1024 * 2;   //  8.4 MB
    u16* Whh_p  = (u16*)p;    p += (size_t)4096 * 2048 * 2;   // 16.8 MB
    u16* xb     = (u16*)p;    p += (size_t)4096 * 1024 * 2;   //  8.4 MB
    u16* GX     = (u16*)p;    p += (size_t)4096 * 4096 * 2;   // 33.6 MB (rows<2047 used)
    u16* Hcat   = (u16*)p;    p += (size_t)4096 * 2048 * 2;   // 16.8 MB
    float* cbA  = (float*)p;  p += (size_t)1024 * 1024 * 4;   //  4.2 MB
    float* cbB  = (float*)p;  p += (size_t)1024 * 1024 * 4;   //  4.2 MB

    // prep_a: xb + Wih_p + bge (~67 MB traffic).
    prep_a<<<8207, 256, 0, stream>>>(W_ih, emb, b_ih, b_hh, Wih_p, xb, bge);

    #define OFF(k) (4096 - (2 << (k)))

    // Whh packers FIRST (8192 tiny blocks), then GX GEMM (1024 blocks):
    // pack BW overlaps the non-BW-bound GEMM instead of queuing behind it.
    gx_pack<<<9216, 256, 0, stream>>>(
        xb, Wih_p, bge, GX, Hcat + (size_t)OFF(10) * 2048, cbA, W_hh, Whh_p);

    const float* cprev = cbA;
    float* cbufs[2] = {cbB, cbA};
    int t = 0;
    for (int k = TREE_DEPTH - 2; k >= 0; --k) {
        const int n = 1 << k;
        const u16* A = Hcat + (size_t)OFF(k) * 2048;
        const u16* GXl = GX + (size_t)(n - 1) * 4096;
        u16* hnext = (k > 0) ? (Hcat + (size_t)OFF(k - 1) * 2048) : nullptr;
        float* cnext = cbufs[t];
        float* outp = (k == 0) ? out : nullptr;

        if (k == 10) {
            // BM=64, BN=128, KG=2, 256 thr: 512 blocks (2/CU).
            fused_level<4, 1, 2, 2><<<dim3(16, 32), 256, 0, stream>>>(
                A, Whh_p, GXl, cprev, hnext, cnext, outp, n);
        } else if (k == 9) {
            // BM=32, BN=128, KG=2, 256 thr: 512 blocks (2/CU).
            fused_level<2, 1, 2, 2><<<dim3(16, 32), 256, 0, stream>>>(
                A, Whh_p, GXl, cprev, hnext, cnext, outp, n);
        } else if (k == 8) {
            // BM=16, BN=64, KG=4, 256 thr: 1024 blocks (4/CU).
            fused_level<1, 1, 1, 4><<<dim3(16, 64), 256, 0, stream>>>(
                A, Whh_p, GXl, cprev, hnext, cnext, outp, n);
        } else {
            // BM=16, BN=64, KG=8, 512 thr: up to 512 blocks.
            const int gx = (n >= 16) ? n / 16 : 1;
            fused_level<1, 1, 1, 8><<<dim3(gx, 64), 512, 0, stream>>>(
                A, Whh_p, GXl, cprev, hnext, cnext, outp, n);
        }
        cprev = cnext; t ^= 1;
    }
}